// Round 2
// baseline (1349.551 us; speedup 1.0000x reference)
//
#include <hip/hip_runtime.h>

#define L_STEPS 1000
#define BATCH   1024

__device__ __forceinline__ float frcp(float x)  { return __builtin_amdgcn_rcpf(x); }
__device__ __forceinline__ float fsig(float x)  { return frcp(1.0f + __expf(-x)); }
__device__ __forceinline__ float ftanh(float x) { return 1.0f - 2.0f * frcp(__expf(2.0f * x) + 1.0f); }

#define FMA4(vv, W, base, A) do { \
    A = fmaf((vv).x, W[(base)+0], A); \
    A = fmaf((vv).y, W[(base)+1], A); \
    A = fmaf((vv).z, W[(base)+2], A); \
    A = fmaf((vv).w, W[(base)+3], A); } while (0)

__global__ __launch_bounds__(64, 1) void vrnn_scan(
    const float* __restrict__ ext, const float* __restrict__ obs, const float* __restrict__ eps,
    const float* __restrict__ puW1, const float* __restrict__ pub1,
    const float* __restrict__ puW2, const float* __restrict__ pub2,
    const float* __restrict__ pxW1, const float* __restrict__ pxb1,
    const float* __restrict__ pxW2, const float* __restrict__ pxb2,
    const float* __restrict__ pzW1, const float* __restrict__ pzb1,
    const float* __restrict__ pzW2, const float* __restrict__ pzb2,
    const float* __restrict__ poW1, const float* __restrict__ pob1,
    const float* __restrict__ poW2, const float* __restrict__ pob2,
    const float* __restrict__ Wmu, const float* __restrict__ bmu,
    const float* __restrict__ Wls, const float* __restrict__ bls,
    const float* __restrict__ Wih, const float* __restrict__ bih,
    const float* __restrict__ Whh, const float* __restrict__ bhh,
    float* __restrict__ out)
{
    const int l   = threadIdx.x;      // 0..63, one wave per block = one batch row
    const int r   = blockIdx.x;       // 0..1023
    const int idx = l >> 2;           // 0..15
    const int p   = l & 3;            // 0..3

    // per-row LDS scratch (~1.1 KB)
    __shared__ __align__(16) float rawbuf[16];   // [0:4]=obs, [4:8]=0, [8:16]=ext
    __shared__ __align__(16) float epsbuf[8];
    __shared__ __align__(16) float h1buf[32];
    __shared__ __align__(16) float in64[64];     // xe | ue | ze | h
    __shared__ __align__(16) float s2buf[48];
    __shared__ __align__(16) float t48[48];
    __shared__ __align__(16) float zbuf[8];
    __shared__ __align__(16) float ze1buf[16];
    __shared__ float bheadb[16];                 // bmu | bls
    __shared__ float brnnb[16];                  // bih + bhh

    // ------------- LDS init -------------
    if (l < 16) {
        rawbuf[l]    = 0.0f;
        in64[48 + l] = 0.0f;                     // h0 = 0
        bheadb[l]    = (l < 8) ? bmu[l] : bls[l - 8];
        brnnb[l]     = bih[l] + bhh[l];
    }

    // ------------- weights -> registers (per-lane columns) -------------
    float wA[48]; float biasA;                   // DBlock pass A: cols 0..47 = W1 col l; 48..63 = W2 col l-48
    {
        const float* baseA;
        if (l < 48) { baseA = poW1 + l;        biasA = pob1[l]; }
        else        { baseA = poW2 + (l - 48); biasA = pob2[l - 48]; }
        #pragma unroll
        for (int k = 0; k < 48; ++k) wA[k] = baseA[k * 48];
    }
    float wB[48]; float biasB;                   // DBlock pass B (lanes 0..31): W2 cols 16..47
    {
        const int c = 16 + (l & 31);             // in-bounds dummy for lanes >= 32 (result discarded)
        const float* baseB = poW2 + c;
        biasB = pob2[c];
        #pragma unroll
        for (int k = 0; k < 48; ++k) wB[k] = baseB[k * 48];
    }
    float whead[12];                             // heads: out idx (mu 0..7 | ls 8..15), k-slice 12p..12p+11
    {
        const float* baseH = (idx < 8) ? (Wmu + idx) : (Wls + (idx - 8));
        #pragma unroll
        for (int i = 0; i < 12; ++i) whead[i] = baseH[(12 * p + i) * 8];
    }
    float wrnn[16];                              // rnn: out idx, k-slice of concat([Wih;Whh]) rows 16p..16p+15
    {
        #pragma unroll
        for (int i = 0; i < 16; ++i) {
            const int c = 16 * p + i;
            const float a = Wih[min(c, 47) * 16 + idx];
            const float b = Whh[max(c - 48, 0) * 16 + idx];
            wrnn[i] = (c < 48) ? a : b;
        }
    }
    const int j16 = l & 15;
    float wpre1[8], wpre2[16], bpre1, bpre2;     // lanes 0..15: px (obs->xe); 16..31: pu (ext->ue)
    {
        const bool isx = (l < 16);
        #pragma unroll
        for (int k = 0; k < 8; ++k) {
            const float xv = pxW1[min(k, 3) * 16 + j16];
            const float uv = puW1[k * 16 + j16];
            float v = isx ? xv : uv;
            if (isx && k >= 4) v = 0.0f;         // pad obs-input to 8 with zeros
            wpre1[k] = v;
        }
        #pragma unroll
        for (int k = 0; k < 16; ++k) {
            const float xv = pxW2[k * 16 + j16];
            const float uv = puW2[k * 16 + j16];
            wpre2[k] = isx ? xv : uv;
        }
        bpre1 = isx ? pxb1[j16] : pub1[j16];
        bpre2 = isx ? pxb2[j16] : pub2[j16];
    }
    float wpz1[8], wpz2[16], bpz1, bpz2;         // z -> z_e MLP, col j16 (lanes 0..15 used)
    {
        #pragma unroll
        for (int k = 0; k < 8; ++k)  wpz1[k] = pzW1[k * 16 + j16];
        #pragma unroll
        for (int k = 0; k < 16; ++k) wpz2[k] = pzW2[k * 16 + j16];
        bpz1 = pzb1[j16];
        bpz2 = pzb2[j16];
    }

    // ------------- input prefetch pointers (role per lane) -------------
    const float* pin; long pstride;
    if (l < 4)                  { pin = obs + (size_t)r * 4 + l;        pstride = 4 * BATCH; }
    else if (l >= 8 && l < 16)  { pin = ext + (size_t)r * 8 + (l - 8);  pstride = 8 * BATCH; }
    else if (l >= 16 && l < 24) { pin = eps + (size_t)r * 8 + (l - 16); pstride = 8 * BATCH; }
    else                        { pin = obs;                            pstride = 0; }

    float vin = *pin;                            // t = 0 data
    pin += pstride;

    // output pointer: mu for idx<8, logsigma for idx>=8 (stored by p==0 lanes)
    float* pout = out + ((idx < 8) ? ((size_t)r * 8 + idx)
                                   : ((size_t)L_STEPS * BATCH * 8 + (size_t)r * 8 + (idx - 8)));

    __syncthreads();

    float hn = 0.0f;

    for (int t = 0; t < L_STEPS; ++t) {
        // ---- stage current inputs to LDS, prefetch next ----
        if (l < 4 || (l >= 8 && l < 16)) rawbuf[l] = vin;
        if (l >= 16 && l < 24)           epsbuf[l - 16] = vin;
        vin = *pin;
        pin += (t < L_STEPS - 2) ? pstride : 0;

        // ---- pre-process: xe (lanes 0-15), ue (lanes 16-31) ----
        {
            const float4* rb = (const float4*)(rawbuf + ((l & 16) ? 8 : 0));
            float4 v0 = rb[0], v1 = rb[1];
            float a1 = bpre1;
            FMA4(v0, wpre1, 0, a1);
            FMA4(v1, wpre1, 4, a1);
            a1 = fmaxf(a1, 0.0f);
            if (l < 32) h1buf[l] = a1;
            const float4* hb = (const float4*)(h1buf + ((l & 16) ? 16 : 0));
            float a2 = bpre2;
            #pragma unroll
            for (int q = 0; q < 4; ++q) { float4 v = hb[q]; FMA4(v, wpre2, 4 * q, a2); }
            a2 = fmaxf(a2, 0.0f);
            if (l < 32) in64[l] = a2;            // xe -> [0:16], ue -> [16:32]
        }

        // ---- DBlock: two 48x48 gemvs sharing the cat reads ----
        float sA = biasA, sB = biasB;
        {
            const float4* c4 = (const float4*)in64;          // xe|ue  (cat rows 0..31)
            #pragma unroll
            for (int q = 0; q < 8; ++q) {
                float4 v = c4[q];
                FMA4(v, wA, 4 * q, sA);
                FMA4(v, wB, 4 * q, sB);
            }
            const float4* h4 = (const float4*)(in64 + 48);   // h (cat rows 32..47)
            #pragma unroll
            for (int q = 0; q < 4; ++q) {
                float4 v = h4[q];
                FMA4(v, wA, 32 + 4 * q, sA);
                FMA4(v, wB, 32 + 4 * q, sB);
            }
        }
        if (l >= 48) s2buf[l - 48] = sA;         // s2[0:16]
        if (l < 32)  s2buf[16 + l] = sB;         // s2[16:48]
        if (l < 48)  t48[l] = ftanh(sA) * fsig(s2buf[l]);

        // ---- heads: mu (idx<8) / logsigma (idx>=8), 4-lane split dot-48 ----
        float acc = 0.0f;
        {
            const float4* tb = (const float4*)(t48 + 12 * p);
            float4 a0 = tb[0], a1v = tb[1], a2v = tb[2];
            FMA4(a0,  whead, 0, acc);
            FMA4(a1v, whead, 4, acc);
            FMA4(a2v, whead, 8, acc);
        }
        acc += __shfl_xor(acc, 1);
        acc += __shfl_xor(acc, 2);
        acc += bheadb[idx];
        if (p == 0) *pout = acc;                 // mu or logsigma
        pout += (size_t)8 * BATCH;

        // ---- z = mu + exp(0.5*ls)*eps ----
        {
            float lsv = __shfl(acc, l | 32);     // pull ls_idx into mu lanes
            if (l < 32) {
                float z = fmaf(__expf(0.5f * lsv), epsbuf[idx], acc);
                if (p == 0) zbuf[idx] = z;
            }
        }

        // ---- z_e = pre(z): 8->16 relu, 16->16 relu (lanes 0..15 produce) ----
        {
            const float4* zb = (const float4*)zbuf;
            float4 z0 = zb[0], z1 = zb[1];
            float a1 = bpz1;
            FMA4(z0, wpz1, 0, a1);
            FMA4(z1, wpz1, 4, a1);
            a1 = fmaxf(a1, 0.0f);
            if (l < 16) ze1buf[l] = a1;
            const float4* zeb = (const float4*)ze1buf;
            float a2 = bpz2;
            #pragma unroll
            for (int q = 0; q < 4; ++q) { float4 v = zeb[q]; FMA4(v, wpz2, 4 * q, a2); }
            a2 = fmaxf(a2, 0.0f);
            if (l < 16) in64[32 + l] = a2;       // ze -> [32:48]
        }

        // ---- RNN: h' = tanh([xe|ue|ze|h] . [Wih;Whh] col idx + b), 4-lane split dot-64 ----
        {
            const float4* ib = (const float4*)(in64 + 16 * p);
            float a = 0.0f;
            #pragma unroll
            for (int q = 0; q < 4; ++q) { float4 v = ib[q]; FMA4(v, wrnn, 4 * q, a); }
            a += __shfl_xor(a, 1);
            a += __shfl_xor(a, 2);
            a += brnnb[idx];
            hn = ftanh(a);
            if (p == 0) in64[48 + idx] = hn;     // h -> [48:64] for next step
        }
    }

    // ---- final hidden state ----
    if (p == 0) out[(size_t)L_STEPS * BATCH * 8 * 2 + (size_t)r * 16 + idx] = hn;
}

extern "C" void kernel_launch(void* const* d_in, const int* in_sizes, int n_in,
                              void* d_out, int out_size, void* d_ws, size_t ws_size,
                              hipStream_t stream) {
    const float* ext  = (const float*)d_in[0];
    const float* obs  = (const float*)d_in[1];
    const float* eps  = (const float*)d_in[2];
    const float* puW1 = (const float*)d_in[3];  const float* pub1 = (const float*)d_in[4];
    const float* puW2 = (const float*)d_in[5];  const float* pub2 = (const float*)d_in[6];
    const float* pxW1 = (const float*)d_in[7];  const float* pxb1 = (const float*)d_in[8];
    const float* pxW2 = (const float*)d_in[9];  const float* pxb2 = (const float*)d_in[10];
    const float* pzW1 = (const float*)d_in[11]; const float* pzb1 = (const float*)d_in[12];
    const float* pzW2 = (const float*)d_in[13]; const float* pzb2 = (const float*)d_in[14];
    const float* poW1 = (const float*)d_in[15]; const float* pob1 = (const float*)d_in[16];
    const float* poW2 = (const float*)d_in[17]; const float* pob2 = (const float*)d_in[18];
    const float* Wmu  = (const float*)d_in[19]; const float* bmu  = (const float*)d_in[20];
    const float* Wls  = (const float*)d_in[21]; const float* bls  = (const float*)d_in[22];
    const float* Wih  = (const float*)d_in[23]; const float* bih  = (const float*)d_in[24];
    const float* Whh  = (const float*)d_in[25]; const float* bhh  = (const float*)d_in[26];
    float* out = (float*)d_out;

    vrnn_scan<<<dim3(BATCH), dim3(64), 0, stream>>>(
        ext, obs, eps,
        puW1, pub1, puW2, pub2,
        pxW1, pxb1, pxW2, pxb2,
        pzW1, pzb1, pzW2, pzb2,
        poW1, pob1, poW2, pob2,
        Wmu, bmu, Wls, bls,
        Wih, bih, Whh, bhh,
        out);
}

// Round 5
// 1348.300 us; speedup vs baseline: 1.0009x; 1.0009x over previous
//
#include <hip/hip_runtime.h>

#define L_STEPS 1000
#define BATCH   1024
#define REC     128   // floats per (t,r) record in workspace: [0:96) s1p/s2p interleaved, [96:112) ihp, rest pad

__device__ __forceinline__ float frcp(float x)  { return __builtin_amdgcn_rcpf(x); }
__device__ __forceinline__ float fsig(float x)  { return frcp(1.0f + __expf(-x)); }
__device__ __forceinline__ float ftanh(float x) { return 1.0f - 2.0f * frcp(__expf(2.0f * x) + 1.0f); }

// quad_perm DPP cross-lane adds (lanes within each 4-lane group)
__device__ __forceinline__ float qxor1(float x) {
    return __int_as_float(__builtin_amdgcn_update_dpp(0, __float_as_int(x), 0xB1, 0xF, 0xF, true));
}
__device__ __forceinline__ float qxor2(float x) {
    return __int_as_float(__builtin_amdgcn_update_dpp(0, __float_as_int(x), 0x4E, 0xF, 0xF, true));
}

#define FMA4(vv, W, base, A) do { \
    A = fmaf((vv).x, W[(base)+0], A); \
    A = fmaf((vv).y, W[(base)+1], A); \
    A = fmaf((vv).z, W[(base)+2], A); \
    A = fmaf((vv).w, W[(base)+3], A); } while (0)

// ===================== Kernel A: parallel precompute =====================
// grid (BATCH/128, L_STEPS), block 128. Thread j of block (rc,t):
//   phase1: compute xe/ue for row rc*128+j -> LDS
//   phase2: compute record element j for all 128 rows of the chunk (coalesced writes)
__global__ __launch_bounds__(128) void vrnn_pre(
    const float* __restrict__ ext, const float* __restrict__ obs,
    const float* __restrict__ puW1, const float* __restrict__ pub1,
    const float* __restrict__ puW2, const float* __restrict__ pub2,
    const float* __restrict__ pxW1, const float* __restrict__ pxb1,
    const float* __restrict__ pxW2, const float* __restrict__ pxb2,
    const float* __restrict__ poW1, const float* __restrict__ pob1,
    const float* __restrict__ poW2, const float* __restrict__ pob2,
    const float* __restrict__ Wih, const float* __restrict__ bih,
    const float* __restrict__ bhh,
    float* __restrict__ ws)
{
    const int j  = threadIdx.x;
    const int rc = blockIdx.x * 128;
    const int t  = blockIdx.y;

    __shared__ float wsm[768];        // px/pu weights+biases staged
    __shared__ float xu[128][36];     // xe|ue per row (padded stride for b128 alignment)

    // offsets: PX1=0(64) PX2=64(256) PU1=320(128) PU2=448(256) BX1=704 BX2=720 BU1=736 BU2=752
    for (int i = j; i < 64;  i += 128) wsm[0   + i] = pxW1[i];
    for (int i = j; i < 256; i += 128) wsm[64  + i] = pxW2[i];
    for (int i = j; i < 128; i += 128) wsm[320 + i] = puW1[i];
    for (int i = j; i < 256; i += 128) wsm[448 + i] = puW2[i];
    if (j < 16) {
        wsm[704 + j] = pxb1[j]; wsm[720 + j] = pxb2[j];
        wsm[736 + j] = pub1[j]; wsm[752 + j] = pub2[j];
    }
    __syncthreads();

    // ---- phase 1: xe/ue for row r = rc + j ----
    {
        const size_t row = (size_t)t * BATCH + rc + j;
        const float* o = obs + row * 4;
        const float* e = ext + row * 8;
        float ob[4], ex[8];
        #pragma unroll
        for (int k = 0; k < 4; ++k) ob[k] = o[k];
        #pragma unroll
        for (int k = 0; k < 8; ++k) ex[k] = e[k];

        float t1[16];
        #pragma unroll
        for (int c = 0; c < 16; ++c) {
            float a = wsm[704 + c];
            #pragma unroll
            for (int k = 0; k < 4; ++k) a = fmaf(ob[k], wsm[0 + k * 16 + c], a);
            t1[c] = fmaxf(a, 0.0f);
        }
        #pragma unroll
        for (int c = 0; c < 16; ++c) {
            float a = wsm[720 + c];
            #pragma unroll
            for (int k = 0; k < 16; ++k) a = fmaf(t1[k], wsm[64 + k * 16 + c], a);
            xu[j][c] = fmaxf(a, 0.0f);                    // xe
        }
        #pragma unroll
        for (int c = 0; c < 16; ++c) {
            float a = wsm[736 + c];
            #pragma unroll
            for (int k = 0; k < 8; ++k) a = fmaf(ex[k], wsm[320 + k * 16 + c], a);
            t1[c] = fmaxf(a, 0.0f);
        }
        #pragma unroll
        for (int c = 0; c < 16; ++c) {
            float a = wsm[752 + c];
            #pragma unroll
            for (int k = 0; k < 16; ++k) a = fmaf(t1[k], wsm[448 + k * 16 + c], a);
            xu[j][16 + c] = fmaxf(a, 0.0f);               // ue
        }
    }

    // ---- phase 2: weight column for record element j ----
    float wc[32]; float bias = 0.0f;
    if (j < 96) {
        const int c = j >> 1;
        const float* W = (j & 1) ? poW2 : poW1;
        bias = (j & 1) ? pob2[c] : pob1[c];
        #pragma unroll
        for (int k = 0; k < 32; ++k) wc[k] = W[k * 48 + c];
    } else if (j < 112) {
        const int c = j - 96;
        bias = bih[c] + bhh[c];
        #pragma unroll
        for (int k = 0; k < 32; ++k) wc[k] = Wih[k * 16 + c];
    } else {
        #pragma unroll
        for (int k = 0; k < 32; ++k) wc[k] = 0.0f;
    }
    __syncthreads();

    float* rb = ws + ((size_t)t * BATCH + rc) * REC + j;
    for (int r = 0; r < 128; ++r) {
        const float4* x4 = (const float4*)&xu[r][0];
        float a = bias;
        #pragma unroll
        for (int q = 0; q < 8; ++q) { float4 v = x4[q]; FMA4(v, wc, 4 * q, a); }
        rb[(size_t)r * REC] = a;
    }
}

// ===================== Kernel B: register-only serial scan =====================
__global__ __launch_bounds__(64, 1) void vrnn_scan2(
    const float* __restrict__ ws, const float* __restrict__ eps,
    const float* __restrict__ poW1, const float* __restrict__ poW2,
    const float* __restrict__ Wmu, const float* __restrict__ bmu,
    const float* __restrict__ Wls, const float* __restrict__ bls,
    const float* __restrict__ pzW1, const float* __restrict__ pzb1,
    const float* __restrict__ pzW2, const float* __restrict__ pzb2,
    const float* __restrict__ Wih, const float* __restrict__ Whh,
    float* __restrict__ out)
{
    const int l   = threadIdx.x;
    const int r   = blockIdx.x;
    const int idx = l >> 2;
    const int p   = l & 3;

    // ---- weights -> registers ----
    const int cl = (l < 48) ? l : 47;            // safe dummy col for lanes 48-63
    float wAh[16], wBh[16];
    #pragma unroll
    for (int k = 0; k < 16; ++k) {
        wAh[k] = poW1[(32 + k) * 48 + cl];
        wBh[k] = poW2[(32 + k) * 48 + cl];
    }
    const int hm = idx & 7;
    const float* WH = (idx < 8) ? Wmu : Wls;
    float whead[12];
    #pragma unroll
    for (int i = 0; i < 12; ++i) whead[i] = WH[(12 * p + i) * 8 + hm];
    const float bhead = (idx < 8) ? bmu[hm] : bls[hm];

    float wr[8];
    #pragma unroll
    for (int i = 0; i < 8; ++i)
        wr[i] = (p < 2) ? Wih[(32 + 8 * (p & 1) + i) * 16 + idx]
                        : Whh[(8 * (p & 1) + i) * 16 + idx];

    const float wz1a = pzW1[(2 * p) * 16 + idx];
    const float wz1b = pzW1[(2 * p + 1) * 16 + idx];
    const float bz1  = pzb1[idx];
    float wz2[4];
    #pragma unroll
    for (int i = 0; i < 4; ++i) wz2[i] = pzW2[(4 * p + i) * 16 + idx];
    const float bz2 = pzb2[idx];

    // ---- stream pointers ----
    const float* recp = ws + (size_t)r * REC + ((l < 48) ? 2 * l : 48 + l);
    const size_t rstride = (size_t)BATCH * REC;
    const float* epsp = eps + (size_t)r * 8 + (l & 7);

    float2 f2 = make_float2(0.0f, 0.0f); float d1 = 0.0f;
    if (l < 48) f2 = *(const float2*)recp; else d1 = *recp;
    float ev = *epsp;
    recp += rstride; epsp += (size_t)8 * BATCH;

    float* pout = out + ((idx < 8) ? ((size_t)r * 8 + idx)
                                   : ((size_t)L_STEPS * BATCH * 8 + (size_t)r * 8 + (idx - 8)));

    float h[16];
    #pragma unroll
    for (int k = 0; k < 16; ++k) h[k] = 0.0f;
    float hn = 0.0f;

    for (int t = 0; t < L_STEPS; ++t) {
        const float s1p = f2.x, s2p = f2.y;
        const float ihpv = d1, epsv = ev;

        // issue next-step prefetch (independent of chain)
        float2 nf2 = make_float2(0.0f, 0.0f); float nd1 = 0.0f;
        if (l < 48) nf2 = *(const float2*)recp; else nd1 = *recp;
        float nev = *epsp;
        recp += (t < L_STEPS - 2) ? rstride : 0;
        epsp += (t < L_STEPS - 2) ? (size_t)8 * BATCH : 0;

        // off-critical-path gathers (issue early)
        const float ihg = __shfl(ihpv, 48 + idx);       // ihp[idx] from lanes 48-63
        const float eg  = __shfl(epsv, idx & 7);        // eps[idx] from lanes 0-7

        // ---- DBlock: sA/sB = precomputed + h-part ----
        #pragma unroll
        for (int k = 0; k < 16; ++k) h[k] = __shfl(hn, 4 * k);   // uniform src -> readlane bcast
        float sA = s1p, sB = s2p;
        #pragma unroll
        for (int k = 0; k < 16; ++k) {
            sA = fmaf(h[k], wAh[k], sA);
            sB = fmaf(h[k], wBh[k], sB);
        }
        const float tt = ftanh(sA) * fsig(sB);          // t48 col l (valid l<48)

        // ---- heads: 4-lane-split dot-48 via shfl gathers ----
        float acc = 0.0f;
        #pragma unroll
        for (int i = 0; i < 12; ++i) acc = fmaf(__shfl(tt, 12 * p + i), whead[i], acc);
        acc += qxor1(acc); acc += qxor2(acc);           // replicated quad sum
        acc += bhead;                                   // mu[idx] (idx<8) | ls[idx-8]
        if (p == 0) *pout = acc;
        pout += (size_t)8 * BATCH;

        // ---- z = mu + exp(0.5 ls)*eps (valid lanes < 32, replicated per quad) ----
        const float other = __shfl(acc, l ^ 32);
        const float zv = fmaf(__expf(0.5f * other), eg, acc);

        // ---- z_e layer 1: 8 -> 16 ----
        float a1 = fmaf(__shfl(zv, 8 * p), wz1a, __shfl(zv, 8 * p + 4) * wz1b);
        a1 += qxor1(a1); a1 += qxor2(a1);
        a1 = fmaxf(a1 + bz1, 0.0f);                     // a1[idx], replicated

        // ---- z_e layer 2: 16 -> 16 ----
        float ze = 0.0f;
        #pragma unroll
        for (int i = 0; i < 4; ++i) ze = fmaf(__shfl(a1, 16 * p + 4 * i), wz2[i], ze);
        ze += qxor1(ze); ze += qxor2(ze);
        ze = fmaxf(ze + bz2, 0.0f);                     // ze[idx], replicated

        // ---- RNN: pre = ihp + ze.Wih[32:48] + h.Whh ----
        float pre = 0.0f;
        #pragma unroll
        for (int i = 0; i < 8; ++i) {
            const float g = __shfl(ze, 4 * (8 * (p & 1) + i));
            const float v = (p < 2) ? g : h[8 * (p & 1) + i];
            pre = fmaf(v, wr[i], pre);
        }
        pre += qxor1(pre); pre += qxor2(pre);
        hn = ftanh(pre + ihg);                          // h'[idx], replicated in all lanes

        f2 = nf2; d1 = nd1; ev = nev;
    }

    if (p == 0) out[(size_t)L_STEPS * BATCH * 8 * 2 + (size_t)r * 16 + idx] = hn;
}

// ===================== Fallback: proven round-2 kernel (ws too small) =====================
__global__ __launch_bounds__(64, 1) void vrnn_scan(
    const float* __restrict__ ext, const float* __restrict__ obs, const float* __restrict__ eps,
    const float* __restrict__ puW1, const float* __restrict__ pub1,
    const float* __restrict__ puW2, const float* __restrict__ pub2,
    const float* __restrict__ pxW1, const float* __restrict__ pxb1,
    const float* __restrict__ pxW2, const float* __restrict__ pxb2,
    const float* __restrict__ pzW1, const float* __restrict__ pzb1,
    const float* __restrict__ pzW2, const float* __restrict__ pzb2,
    const float* __restrict__ poW1, const float* __restrict__ pob1,
    const float* __restrict__ poW2, const float* __restrict__ pob2,
    const float* __restrict__ Wmu, const float* __restrict__ bmu,
    const float* __restrict__ Wls, const float* __restrict__ bls,
    const float* __restrict__ Wih, const float* __restrict__ bih,
    const float* __restrict__ Whh, const float* __restrict__ bhh,
    float* __restrict__ out)
{
    const int l   = threadIdx.x;
    const int r   = blockIdx.x;
    const int idx = l >> 2;
    const int p   = l & 3;

    __shared__ __align__(16) float rawbuf[16];
    __shared__ __align__(16) float epsbuf[8];
    __shared__ __align__(16) float h1buf[32];
    __shared__ __align__(16) float in64[64];
    __shared__ __align__(16) float s2buf[48];
    __shared__ __align__(16) float t48[48];
    __shared__ __align__(16) float zbuf[8];
    __shared__ __align__(16) float ze1buf[16];
    __shared__ float bheadb[16];
    __shared__ float brnnb[16];

    if (l < 16) {
        rawbuf[l]    = 0.0f;
        in64[48 + l] = 0.0f;
        bheadb[l]    = (l < 8) ? bmu[l] : bls[l - 8];
        brnnb[l]     = bih[l] + bhh[l];
    }

    float wA[48]; float biasA;
    {
        const float* baseA;
        if (l < 48) { baseA = poW1 + l;        biasA = pob1[l]; }
        else        { baseA = poW2 + (l - 48); biasA = pob2[l - 48]; }
        #pragma unroll
        for (int k = 0; k < 48; ++k) wA[k] = baseA[k * 48];
    }
    float wB[48]; float biasB;
    {
        const int c = 16 + (l & 31);
        const float* baseB = poW2 + c;
        biasB = pob2[c];
        #pragma unroll
        for (int k = 0; k < 48; ++k) wB[k] = baseB[k * 48];
    }
    float whead[12];
    {
        const float* baseH = (idx < 8) ? (Wmu + idx) : (Wls + (idx - 8));
        #pragma unroll
        for (int i = 0; i < 12; ++i) whead[i] = baseH[(12 * p + i) * 8];
    }
    float wrnn[16];
    {
        #pragma unroll
        for (int i = 0; i < 16; ++i) {
            const int c = 16 * p + i;
            const float a = Wih[min(c, 47) * 16 + idx];
            const float b = Whh[max(c - 48, 0) * 16 + idx];
            wrnn[i] = (c < 48) ? a : b;
        }
    }
    const int j16 = l & 15;
    float wpre1[8], wpre2[16], bpre1, bpre2;
    {
        const bool isx = (l < 16);
        #pragma unroll
        for (int k = 0; k < 8; ++k) {
            const float xv = pxW1[min(k, 3) * 16 + j16];
            const float uv = puW1[k * 16 + j16];
            float v = isx ? xv : uv;
            if (isx && k >= 4) v = 0.0f;
            wpre1[k] = v;
        }
        #pragma unroll
        for (int k = 0; k < 16; ++k) {
            const float xv = pxW2[k * 16 + j16];
            const float uv = puW2[k * 16 + j16];
            wpre2[k] = isx ? xv : uv;
        }
        bpre1 = isx ? pxb1[j16] : pub1[j16];
        bpre2 = isx ? pxb2[j16] : pub2[j16];
    }
    float wpz1[8], wpz2[16], bpz1, bpz2;
    {
        #pragma unroll
        for (int k = 0; k < 8; ++k)  wpz1[k] = pzW1[k * 16 + j16];
        #pragma unroll
        for (int k = 0; k < 16; ++k) wpz2[k] = pzW2[k * 16 + j16];
        bpz1 = pzb1[j16];
        bpz2 = pzb2[j16];
    }

    const float* pin; long pstride;
    if (l < 4)                  { pin = obs + (size_t)r * 4 + l;        pstride = 4 * BATCH; }
    else if (l >= 8 && l < 16)  { pin = ext + (size_t)r * 8 + (l - 8);  pstride = 8 * BATCH; }
    else if (l >= 16 && l < 24) { pin = eps + (size_t)r * 8 + (l - 16); pstride = 8 * BATCH; }
    else                        { pin = obs;                            pstride = 0; }

    float vin = *pin;
    pin += pstride;

    float* pout = out + ((idx < 8) ? ((size_t)r * 8 + idx)
                                   : ((size_t)L_STEPS * BATCH * 8 + (size_t)r * 8 + (idx - 8)));

    __syncthreads();

    float hn = 0.0f;

    for (int t = 0; t < L_STEPS; ++t) {
        if (l < 4 || (l >= 8 && l < 16)) rawbuf[l] = vin;
        if (l >= 16 && l < 24)           epsbuf[l - 16] = vin;
        vin = *pin;
        pin += (t < L_STEPS - 2) ? pstride : 0;

        {
            const float4* rb = (const float4*)(rawbuf + ((l & 16) ? 8 : 0));
            float4 v0 = rb[0], v1 = rb[1];
            float a1 = bpre1;
            FMA4(v0, wpre1, 0, a1);
            FMA4(v1, wpre1, 4, a1);
            a1 = fmaxf(a1, 0.0f);
            if (l < 32) h1buf[l] = a1;
            const float4* hb = (const float4*)(h1buf + ((l & 16) ? 16 : 0));
            float a2 = bpre2;
            #pragma unroll
            for (int q = 0; q < 4; ++q) { float4 v = hb[q]; FMA4(v, wpre2, 4 * q, a2); }
            a2 = fmaxf(a2, 0.0f);
            if (l < 32) in64[l] = a2;
        }

        float sA = biasA, sB = biasB;
        {
            const float4* c4 = (const float4*)in64;
            #pragma unroll
            for (int q = 0; q < 8; ++q) {
                float4 v = c4[q];
                FMA4(v, wA, 4 * q, sA);
                FMA4(v, wB, 4 * q, sB);
            }
            const float4* h4 = (const float4*)(in64 + 48);
            #pragma unroll
            for (int q = 0; q < 4; ++q) {
                float4 v = h4[q];
                FMA4(v, wA, 32 + 4 * q, sA);
                FMA4(v, wB, 32 + 4 * q, sB);
            }
        }
        if (l >= 48) s2buf[l - 48] = sA;
        if (l < 32)  s2buf[16 + l] = sB;
        if (l < 48)  t48[l] = ftanh(sA) * fsig(s2buf[l]);

        float acc = 0.0f;
        {
            const float4* tb = (const float4*)(t48 + 12 * p);
            float4 a0 = tb[0], a1v = tb[1], a2v = tb[2];
            FMA4(a0,  whead, 0, acc);
            FMA4(a1v, whead, 4, acc);
            FMA4(a2v, whead, 8, acc);
        }
        acc += __shfl_xor(acc, 1);
        acc += __shfl_xor(acc, 2);
        acc += bheadb[idx];
        if (p == 0) *pout = acc;
        pout += (size_t)8 * BATCH;

        {
            float lsv = __shfl(acc, l | 32);
            if (l < 32) {
                float z = fmaf(__expf(0.5f * lsv), epsbuf[idx], acc);
                if (p == 0) zbuf[idx] = z;
            }
        }

        {
            const float4* zb = (const float4*)zbuf;
            float4 z0 = zb[0], z1 = zb[1];
            float a1 = bpz1;
            FMA4(z0, wpz1, 0, a1);
            FMA4(z1, wpz1, 4, a1);
            a1 = fmaxf(a1, 0.0f);
            if (l < 16) ze1buf[l] = a1;
            const float4* zeb = (const float4*)ze1buf;
            float a2 = bpz2;
            #pragma unroll
            for (int q = 0; q < 4; ++q) { float4 v = zeb[q]; FMA4(v, wpz2, 4 * q, a2); }
            a2 = fmaxf(a2, 0.0f);
            if (l < 16) in64[32 + l] = a2;
        }

        {
            const float4* ib = (const float4*)(in64 + 16 * p);
            float a = 0.0f;
            #pragma unroll
            for (int q = 0; q < 4; ++q) { float4 v = ib[q]; FMA4(v, wrnn, 4 * q, a); }
            a += __shfl_xor(a, 1);
            a += __shfl_xor(a, 2);
            a += brnnb[idx];
            hn = ftanh(a);
            if (p == 0) in64[48 + idx] = hn;
        }
    }

    if (p == 0) out[(size_t)L_STEPS * BATCH * 8 * 2 + (size_t)r * 16 + idx] = hn;
}

extern "C" void kernel_launch(void* const* d_in, const int* in_sizes, int n_in,
                              void* d_out, int out_size, void* d_ws, size_t ws_size,
                              hipStream_t stream) {
    const float* ext  = (const float*)d_in[0];
    const float* obs  = (const float*)d_in[1];
    const float* eps  = (const float*)d_in[2];
    const float* puW1 = (const float*)d_in[3];  const float* pub1 = (const float*)d_in[4];
    const float* puW2 = (const float*)d_in[5];  const float* pub2 = (const float*)d_in[6];
    const float* pxW1 = (const float*)d_in[7];  const float* pxb1 = (const float*)d_in[8];
    const float* pxW2 = (const float*)d_in[9];  const float* pxb2 = (const float*)d_in[10];
    const float* pzW1 = (const float*)d_in[11]; const float* pzb1 = (const float*)d_in[12];
    const float* pzW2 = (const float*)d_in[13]; const float* pzb2 = (const float*)d_in[14];
    const float* poW1 = (const float*)d_in[15]; const float* pob1 = (const float*)d_in[16];
    const float* poW2 = (const float*)d_in[17]; const float* pob2 = (const float*)d_in[18];
    const float* Wmu  = (const float*)d_in[19]; const float* bmu  = (const float*)d_in[20];
    const float* Wls  = (const float*)d_in[21]; const float* bls  = (const float*)d_in[22];
    const float* Wih  = (const float*)d_in[23]; const float* bih  = (const float*)d_in[24];
    const float* Whh  = (const float*)d_in[25]; const float* bhh  = (const float*)d_in[26];
    float* out = (float*)d_out;

    const size_t need = (size_t)L_STEPS * BATCH * REC * sizeof(float);
    if (ws_size >= need) {
        float* ws = (float*)d_ws;
        vrnn_pre<<<dim3(BATCH / 128, L_STEPS), dim3(128), 0, stream>>>(
            ext, obs, puW1, pub1, puW2, pub2, pxW1, pxb1, pxW2, pxb2,
            poW1, pob1, poW2, pob2, Wih, bih, bhh, ws);
        vrnn_scan2<<<dim3(BATCH), dim3(64), 0, stream>>>(
            ws, eps, poW1, poW2, Wmu, bmu, Wls, bls,
            pzW1, pzb1, pzW2, pzb2, Wih, Whh, out);
    } else {
        vrnn_scan<<<dim3(BATCH), dim3(64), 0, stream>>>(
            ext, obs, eps,
            puW1, pub1, puW2, pub2,
            pxW1, pxb1, pxW2, pxb2,
            pzW1, pzb1, pzW2, pzb2,
            poW1, pob1, poW2, pob2,
            Wmu, bmu, Wls, bls,
            Wih, bih, Whh, bhh,
            out);
    }
}